// Round 4
// baseline (184.688 us; speedup 1.0000x reference)
//
#include <hip/hip_runtime.h>
#include <cstdint>
#include <cstddef>

// SLSTM cell, B=4096 IN=1024 HID=2048 GATE=8192, NH=8 HS=256.
// v4: BK=32 uniform K-loop with h interleaved (phi1 = x-tile 32 MFMA, phi2 =
// h-tile 8 MFMA), m201-style read-early phases, uniform vmcnt(4) ledger,
// no LDS swizzle (BK32 is bank-balanced), epilogue c/m/n staged via
// global_load_lds into freed buffers (4 pipelined chunks).

typedef unsigned short u16;
typedef unsigned int   u32;
typedef __bf16 bf16x8 __attribute__((ext_vector_type(8)));
typedef float  f32x4  __attribute__((ext_vector_type(4)));

__device__ __forceinline__ u16 f2bf(float f) {
  u32 u = __builtin_bit_cast(u32, f);
  u32 r = (u + 0x7fffu + ((u >> 16) & 1u)) >> 16;   // RNE
  return (u16)r;
}

__device__ __forceinline__ void gll16(const void* g, void* l) {
  __builtin_amdgcn_global_load_lds(
      (__attribute__((address_space(1))) void*)(uintptr_t)g,
      (__attribute__((address_space(3))) void*)l, 16, 0, 0);
}
__device__ __forceinline__ void gll4(const void* g, void* l) {
  __builtin_amdgcn_global_load_lds(
      (__attribute__((address_space(1))) void*)(uintptr_t)g,
      (__attribute__((address_space(3))) void*)l, 4, 0, 0);
}

// ---------------- cast f32 -> bf16, 8 elems/thread ----------------
__global__ void cast_bf16_kernel(const float* __restrict__ src, u16* __restrict__ dst, int n8) {
  int i = blockIdx.x * blockDim.x + threadIdx.x;
  if (i >= n8) return;
  const float4* s = reinterpret_cast<const float4*>(src) + (size_t)i * 2;
  float4 a = s[0], b = s[1];
  union { u16 h[8]; uint4 v; } o;
  o.h[0] = f2bf(a.x); o.h[1] = f2bf(a.y); o.h[2] = f2bf(a.z); o.h[3] = f2bf(a.w);
  o.h[4] = f2bf(b.x); o.h[5] = f2bf(b.y); o.h[6] = f2bf(b.z); o.h[7] = f2bf(b.w);
  reinterpret_cast<uint4*>(dst)[i] = o.v;
}

// ---------------- pack W transposed: WpackT[g][r], g<8192, r<1280 ----------------
__global__ void pack_w_kernel(const float* __restrict__ Wi, const float* __restrict__ Wh,
                              u16* __restrict__ Wt) {
  __shared__ u16 tile[64][65];
  const int g0 = blockIdx.x * 64;
  const int r0 = blockIdx.y * 64;
  const int tx = threadIdx.x;
  const int ty = threadIdx.y;
  #pragma unroll
  for (int i = 0; i < 4; ++i) {
    const int rr = ty + 16 * i;
    const int r = r0 + rr;
    const int g = g0 + tx;
    float v;
    if (r < 1024) v = Wi[(size_t)r * 8192 + g];
    else {
      const int head = g >> 10;
      v = Wh[(size_t)(head * 256 + (r - 1024)) * 1024 + (g & 1023)];
    }
    tile[rr][tx] = f2bf(v);
  }
  __syncthreads();
  #pragma unroll
  for (int i = 0; i < 4; ++i) {
    const int gg = ty + 16 * i;
    Wt[(size_t)(g0 + gg) * 1280 + r0 + tx] = tile[tx][gg];
  }
}

// ---------------- fused GEMM (K=1280, h interleaved) + gate epilogue ----------------
// 512 blocks: 16 row-blocks (256 rows) x 32 j-blocks (64 j x 4 gates).
// 8 waves (wr 0..1, wj 0..3): wave owns 128 rows x 16 j x 4 gates (acc 4x8 f32x4).
// LDS (u16 units): xA[2]@0/8192, xB[2]@16384/24576, hA[2]@32768/40960,
// hB[2]@49152/51200. Total 53248 u16 = 104 KiB. Epilogue reuses xA/xB/hA.
__global__ __launch_bounds__(512, 2) void slstm_main(
    const u16* __restrict__ xb, const u16* __restrict__ hb, const u16* __restrict__ Wt,
    const float* __restrict__ b_i, const float* __restrict__ b_h,
    const float* __restrict__ c_in, const float* __restrict__ m_in, const float* __restrict__ n_in,
    float* __restrict__ out)
{
  extern __shared__ __align__(16) u16 lds[];

  const int tid = threadIdx.x, lane = tid & 63, w = tid >> 6;
  const int wr = w >> 2, wj = w & 3;

  // bijective XCD-aware swizzle: 512 blocks, 64/XCD
  const int d = blockIdx.x;
  const int xcd = d & 7, loc = d >> 3;
  const int row_blk = (xcd & 3) * 4 + (loc & 3);       // 0..15
  const int j_blk   = (xcd >> 2) * 16 + (loc >> 2);    // 0..31
  const int row0 = row_blk * 256;
  const int j0   = j_blk * 64;
  const int jh   = (j0 >= 1024) ? 1 : 0;

  const int l15 = lane & 15, l4 = lane >> 4;

#define BAR() asm volatile("s_barrier" ::: "memory")
#define WAITV(N) asm volatile("s_waitcnt vmcnt(" #N ")" ::: "memory")

  // ---- biases (hoisted; drained before ledger starts) ----
  const int gj = j0 + wj * 16 + l15;
  const float bias0 = b_i[gj]        + b_h[gj];
  const float bias1 = b_i[2048 + gj] + b_h[2048 + gj];
  const float bias2 = b_i[4096 + gj] + b_h[4096 + gj];
  const float bias3 = b_i[6144 + gj] + b_h[6144 + gj];
  WAITV(0);

  // ---- per-lane staging constants ----
  const int rA  = (w * 64 + lane) >> 2;    // 0..127
  const int kcA = lane & 3;                // k-chunk (8 u16)
  const size_t aX0 = (size_t)(row0 + rA) * 1024 + kcA * 8;
  const size_t aX1 = aX0 + (size_t)128 * 1024;
  const size_t wB0 = ((size_t)((rA >> 6) * 2048 + j0 + (rA & 63))) * 1280 + kcA * 8;
  const size_t wB1 = wB0 + (size_t)2 * 2048 * 1280;
  const size_t hA0s = (size_t)(row0 + rA) * 2048 + kcA * 8;
  const size_t hA1s = hA0s + (size_t)128 * 2048;
  const int cB4 = (w * 64 + lane) >> 4;    // 0..31
  const size_t hB0c = (size_t)(j0 + cB4) * 1280 + 1024 + (lane & 15) * 2;
  const size_t hB1c = (size_t)(j0 + 32 + cB4) * 1280 + 1024 + (lane & 15) * 2;
  const int dA  = (w * 64 + lane) * 8;     // u16 units, lane*16B
  const int dHB = (w * 64 + lane) * 2;     // u16 units, lane*4B

  // ---- fragment read offsets (u16 units, no swizzle needed at BK32) ----
  const int aRd0 = (wr * 128 + l15) * 32 + l4 * 8;   // + f*512 (+32768 for hA)
  const int bRd0 = (wj * 16 + l15) * 32 + l4 * 8;    // + q*2048 (xB) / hB direct

  f32x4 acc[4][8];
  #pragma unroll
  for (int q = 0; q < 4; ++q)
    #pragma unroll
    for (int f = 0; f < 8; ++f)
      acc[q][f] = f32x4{0.0f, 0.0f, 0.0f, 0.0f};

#define ISSUE_X(T) do { const int p_ = (T) & 1; \
    gll16(xb + aX0 + (size_t)(T) * 32, lds + p_ * 8192 + dA); \
    gll16(xb + aX1 + (size_t)(T) * 32, lds + p_ * 8192 + dA + 4096); \
    gll16(Wt + wB0 + (size_t)(T) * 32, lds + 16384 + p_ * 8192 + dA); \
    gll16(Wt + wB1 + (size_t)(T) * 32, lds + 16384 + p_ * 8192 + dA + 4096); } while (0)

#define ISSUE_H(T) do { const int p_ = (T) & 1; const int qv_ = (T) >> 3; \
    const size_t ho_ = (size_t)(2 * qv_ + jh) * 256 + ((T) & 7) * 32; \
    gll16(hb + hA0s + ho_, lds + 32768 + p_ * 8192 + dA); \
    gll16(hb + hA1s + ho_, lds + 32768 + p_ * 8192 + dA + 4096); \
    const size_t qo_ = (size_t)qv_ * 2621440 + ((T) & 7) * 32; \
    gll4(Wt + hB0c + qo_, lds + 49152 + p_ * 2048 + dHB); \
    gll4(Wt + hB1c + qo_, lds + 49152 + p_ * 2048 + dHB + 1024); } while (0)

// epilogue chunk staging: 48 loads (3 tensors x 16), 6/wave, into parity bufs
#define ESTAGE(C, I0, I1) do { \
    _Pragma("unroll") for (int i_ = (I0); i_ < (I1); ++i_) { \
      const int ix_ = w * 6 + i_; \
      const int T_ = ix_ >> 4; \
      const int g_ = ix_ & 15; \
      const float* sp_ = (T_ == 0) ? c_in : ((T_ == 1) ? m_in : n_in); \
      const float* s_ = sp_ + (size_t)(row0 + (g_ >> 3) * 128 + (C) * 32 + (g_ & 7) * 4 + (lane >> 4)) * 2048 \
                        + j0 + (lane & 15) * 4; \
      const int tb_ = (T_ == 0) ? 0 : ((T_ == 1) ? 16384 : 32768); \
      gll16(s_, lds + tb_ + ((C) & 1) * 8192 + g_ * 512 + lane * 8); \
    } } while (0)

#define PHI1(T, ISS) do { const int p_ = (T) & 1; \
    bf16x8 aF[8]; bf16x8 bF[4]; \
    _Pragma("unroll") for (int f_ = 0; f_ < 8; ++f_) \
      aF[f_] = *(const bf16x8*)(lds + p_ * 8192 + aRd0 + f_ * 512); \
    _Pragma("unroll") for (int q_ = 0; q_ < 4; ++q_) \
      bF[q_] = *(const bf16x8*)(lds + 16384 + p_ * 8192 + bRd0 + q_ * 2048); \
    ISS; \
    BAR(); \
    __builtin_amdgcn_s_setprio(1); \
    _Pragma("unroll") for (int q_ = 0; q_ < 4; ++q_) \
      _Pragma("unroll") for (int f_ = 0; f_ < 8; ++f_) \
        acc[q_][f_] = __builtin_amdgcn_mfma_f32_16x16x32_bf16(aF[f_], bF[q_], acc[q_][f_], 0, 0, 0); \
    __builtin_amdgcn_s_setprio(0); \
    WAITV(4); BAR(); } while (0)

#define PHI2(QQ, T, ISS) do { const int p_ = (T) & 1; \
    bf16x8 hFa[8]; bf16x8 hFb; \
    _Pragma("unroll") for (int f_ = 0; f_ < 8; ++f_) \
      hFa[f_] = *(const bf16x8*)(lds + 32768 + p_ * 8192 + aRd0 + f_ * 512); \
    hFb = *(const bf16x8*)(lds + 49152 + p_ * 2048 + bRd0); \
    ISS; \
    BAR(); \
    __builtin_amdgcn_s_setprio(1); \
    _Pragma("unroll") for (int f_ = 0; f_ < 8; ++f_) \
      acc[QQ][f_] = __builtin_amdgcn_mfma_f32_16x16x32_bf16(hFa[f_], hFb, acc[QQ][f_], 0, 0, 0); \
    __builtin_amdgcn_s_setprio(0); \
    WAITV(4); BAR(); } while (0)

  // ---- prologue: X0, H0 in flight; drain X0 ----
  ISSUE_X(0); ISSUE_H(0);
  WAITV(4); BAR();

  // ---- main loop: 32 BK32 tiles (t=31 peeled for epilogue staging) ----
  #pragma unroll
  for (int qt = 0; qt < 4; ++qt) {
    const int tEnd = (qt == 3) ? 7 : 8;
    #pragma unroll 2
    for (int ts = 0; ts < tEnd; ++ts) {
      const int t = qt * 8 + ts;
      PHI1(t, ISSUE_X(t + 1));
      PHI2(qt, t, ISSUE_H(t + 1));
    }
  }
  // t = 31: stage epilogue chunk 0 instead of next tiles
  PHI1(31, ESTAGE(0, 0, 4));
  { // PHI2 tail (no trailing wait; epilogue handles)
    bf16x8 hFa[8]; bf16x8 hFb;
    #pragma unroll
    for (int f_ = 0; f_ < 8; ++f_)
      hFa[f_] = *(const bf16x8*)(lds + 32768 + 8192 + aRd0 + f_ * 512);
    hFb = *(const bf16x8*)(lds + 49152 + 2048 + bRd0);
    ESTAGE(0, 4, 6);
    BAR();
    __builtin_amdgcn_s_setprio(1);
    #pragma unroll
    for (int f_ = 0; f_ < 8; ++f_)
      acc[3][f_] = __builtin_amdgcn_mfma_f32_16x16x32_bf16(hFa[f_], hFb, acc[3][f_], 0, 0, 0);
    __builtin_amdgcn_s_setprio(0);
  }

  // ---- epilogue: 4 pipelined chunks, gates + state update ----
  // C layout (16x16x32): col = lane&15, row = (lane>>4)*4 + reg
#define ECOMP(C) do { \
    const float* pc_ = (const float*)(lds + ((C) & 1) * 8192); \
    const float* pm_ = (const float*)(lds + 16384 + ((C) & 1) * 8192); \
    const float* pn_ = (const float*)(lds + 32768 + ((C) & 1) * 8192); \
    _Pragma("unroll") for (int fi_ = 0; fi_ < 2; ++fi_) { \
      const int f_ = 2 * (C) + fi_; \
      _Pragma("unroll") for (int r_ = 0; r_ < 4; ++r_) { \
        const int rl_ = fi_ * 16 + l4 * 4 + r_; \
        const int fx_ = wr * 2048 + rl_ * 64 + wj * 16 + l15; \
        const float cv = pc_[fx_], mv = pm_[fx_], nv = pn_[fx_]; \
        const float it = acc[0][f_][r_] + bias0; \
        const float ft = acc[1][f_][r_] + bias1; \
        const float zt = acc[2][f_][r_] + bias2; \
        const float ot = acc[3][f_][r_] + bias3; \
        const float mn = fmaxf(ft + mv, it); \
        const float iv = __expf(it - mn); \
        const float fv = __expf(ft - mn + mv); \
        const float az = fabsf(zt); \
        const float e2 = __expf(-2.0f * az); \
        const float tz = (1.0f - e2) / (1.0f + e2); \
        const float zv = (zt >= 0.0f) ? tz : -tz; \
        const float ov = 1.0f / (1.0f + __expf(-ot)); \
        const float cn = fv * cv + iv * zv; \
        const float nn = fv * nv + iv; \
        const float hn = ov * (cn / nn); \
        const int gb = row0 + wr * 128 + f_ * 16 + l4 * 4 + r_; \
        const size_t idx = (size_t)gb * 2048 + gj; \
        out[idx]            = hn; \
        out[ 8388608 + idx] = cn; \
        out[16777216 + idx] = mn; \
        out[25165824 + idx] = nn; \
      } } } while (0)

  WAITV(0); BAR();
  ESTAGE(1, 0, 6); ECOMP(0); WAITV(6); BAR();
  ESTAGE(2, 0, 6); ECOMP(1); WAITV(6); BAR();
  ESTAGE(3, 0, 6); ECOMP(2); WAITV(6); BAR();
  ECOMP(3);

#undef BAR
#undef WAITV
#undef ISSUE_X
#undef ISSUE_H
#undef ESTAGE
#undef PHI1
#undef PHI2
#undef ECOMP
}

extern "C" void kernel_launch(void* const* d_in, const int* in_sizes, int n_in,
                              void* d_out, int out_size, void* d_ws, size_t ws_size,
                              hipStream_t stream) {
  (void)in_sizes; (void)n_in; (void)out_size; (void)ws_size;
  const float* x  = (const float*)d_in[0];
  const float* h  = (const float*)d_in[1];
  const float* c  = (const float*)d_in[2];
  const float* m  = (const float*)d_in[3];
  const float* n  = (const float*)d_in[4];
  const float* Wi = (const float*)d_in[5];
  const float* bi = (const float*)d_in[6];
  const float* Wh = (const float*)d_in[7];
  const float* bh = (const float*)d_in[8];
  float* out = (float*)d_out;

  // workspace (bf16): WpackT 8192x1280 | xb 4096x1024 | hb 4096x2048 (~45MB)
  u16* Wt = (u16*)d_ws;
  u16* xb = Wt + (size_t)8192 * 1280;
  u16* hb = xb + (size_t)4096 * 1024;

  hipFuncSetAttribute((const void*)slstm_main,
                      hipFuncAttributeMaxDynamicSharedMemorySize, 106496);

  cast_bf16_kernel<<<2048, 256, 0, stream>>>(x, xb, 4096 * 1024 / 8);
  cast_bf16_kernel<<<4096, 256, 0, stream>>>(h, hb, 4096 * 2048 / 8);
  pack_w_kernel<<<dim3(128, 20), dim3(64, 16), 0, stream>>>(Wi, Wh, Wt);
  slstm_main<<<512, 512, 106496, stream>>>(xb, hb, Wt, bi, bh, c, m, n, out);
}